// Round 7
// baseline (4115.639 us; speedup 1.0000x reference)
//
#include <hip/hip_runtime.h>

using short8 = __attribute__((ext_vector_type(8))) short;
using f32x4  = __attribute__((ext_vector_type(4))) float;

typedef unsigned short u16;
typedef unsigned int   u32;

#define T_SEQ 256
#define BATCH 64
#define INP   256
#define HID   1024
#define GDIM  4096
#define KC    1280   // HID + INP
#define OUTD  1024

#define NSL   40     // K slices of 32 (32 h + 8 x)
#define NBLK  128    // one block handles BOTH directions
#define LDSB  (2 * NSL * 2 * 64 * 8 * 2)   // 163840 B (full 160 KiB)

#define MFMA16(a,b,c) __builtin_amdgcn_mfma_f32_16x16x32_bf16(a,b,c,0,0,0)

__device__ __forceinline__ u16 f2bf(float f){
  union { float f; u32 u; } v; v.f = f;
  u32 r = v.u + 0x7fffu + ((v.u >> 16) & 1u);
  return (u16)(r >> 16);
}
__device__ __forceinline__ float sigm(float x){ return 1.f/(1.f+__expf(-x)); }
__device__ __forceinline__ float tanhf_(float x){ return 1.f - 2.f/(__expf(2.f*x)+1.f); }

__device__ __forceinline__ void st_u32_wt(u32* p, u32 v){
  asm volatile("global_store_dword %0, %1, off sc0 sc1" :: "v"(p), "v"(v) : "memory");
}
__device__ __forceinline__ void st_f32_wt(float* p, float v){
  asm volatile("global_store_dword %0, %1, off sc0 sc1" :: "v"(p), "v"(v) : "memory");
}

// quad-perm DPP (xor within lane bits 0-1; gate lanes live in one quad)
template<int CTRL>
__device__ __forceinline__ float qperm(float v){
  union { float f; int i; } u; u.f = v;
  u.i = __builtin_amdgcn_mov_dpp(u.i, CTRL, 0xf, 0xf, true);
  return u.f;
}
#define QP_XOR1 177   // quad_perm [1,0,3,2]
#define QP_XOR2 78    // quad_perm [2,3,0,1]

// ---------------------------------------------------------------------------
// Prep: combined recurrent weights, bf16, block-permuted column order (r5).
// Block nb owns gate-cols [nb*32, nb*32+32); n = nb*32 + nt*16 + rq*4 + gate,
// h-col j = nb*8 + 2*rq + nt. Rows k<1024 -> Wh, k>=1024 -> Wx.
// ---------------------------------------------------------------------------
__global__ void build_wc(const float* __restrict__ WhF, const float* __restrict__ WxF,
                         const float* __restrict__ WhB, const float* __restrict__ WxB,
                         u16* __restrict__ WcF, u16* __restrict__ WcB)
{
  const int z = blockIdx.z; const int dir = z >> 2, gate = z & 3;
  const float* Wh = dir ? WhB : WhF;
  const float* Wx = dir ? WxB : WxF;
  u16* Wc = dir ? WcB : WcF;
  const int k0 = blockIdx.x * 64, j0 = blockIdx.y * 64;
  __shared__ float tile[64][65];
  const int t = threadIdx.x;
  #pragma unroll
  for (int i = 0; i < 16; ++i) {
    int idx = i*256 + t; int kr = idx >> 6, jc = idx & 63;
    int k = k0 + kr;
    float v = (k < HID) ? Wh[(size_t)k*GDIM + gate*HID + j0 + jc]
                        : Wx[(size_t)(k-HID)*GDIM + gate*HID + j0 + jc];
    tile[kr][jc] = v;
  }
  __syncthreads();
  #pragma unroll
  for (int i = 0; i < 16; ++i) {
    int idx = i*256 + t; int jc = idx >> 6, kr = idx & 63;
    int j  = j0 + jc;
    int nb = j >> 3, jl = j & 7;
    int nt = jl & 1, rq = jl >> 1;
    int n  = nb*32 + nt*16 + rq*4 + gate;
    Wc[(size_t)n*KC + k0 + kr] = f2bf(tile[kr][jc]);
  }
}

__global__ void build_wfc(const float* __restrict__ Wfc, u16* __restrict__ WfcT)
{
  const int k0 = blockIdx.x * 64;
  const int n0 = blockIdx.y * 64;
  __shared__ float tile[64][65];
  const int t = threadIdx.x;
  #pragma unroll
  for (int i = 0; i < 16; ++i) {
    int idx = i*256 + t; int kr = idx >> 6, nc = idx & 63;
    tile[kr][nc] = Wfc[(size_t)(k0+kr)*OUTD + n0 + nc];
  }
  __syncthreads();
  #pragma unroll
  for (int i = 0; i < 16; ++i) {
    int idx = i*256 + t; int nc = idx >> 6, kr = idx & 63;
    WfcT[(size_t)(n0+nc)*2048 + k0 + kr] = f2bf(tile[kr][nc]);
  }
}

__global__ void conv_x(const float* __restrict__ x, u16* __restrict__ xb, int n)
{
  int i = (blockIdx.x * blockDim.x + threadIdx.x) * 4;
  if (i < n) {
    float4 v = *(const float4*)(x + i);
    u32 lo = (u32)f2bf(v.x) | ((u32)f2bf(v.y) << 16);
    u32 hi = (u32)f2bf(v.z) | ((u32)f2bf(v.w) << 16);
    *(uint2*)(xb + i) = make_uint2(lo, hi);
  }
}

// ---------------------------------------------------------------------------
// helpers for the persistent kernel
// ---------------------------------------------------------------------------
__device__ __forceinline__ void ld_chunk(short8* d, const u16* ar, int c0, int q){
  #pragma unroll
  for (int i = 0; i < 8; ++i) d[i] = *(const short8*)(ar + (c0 + i)*32 + q*8);
}

// ---------------------------------------------------------------------------
// Persistent bidirectional LSTM, fused directions.
// 128 blocks; block nb owns gate-cols [nb*32,nb*32+32) of BOTH dirs.
// Both B panels resident in 160KB LDS. c in registers. Wave w owns batch
// rows [16w,16w+16) -> per-wave flags, no __syncthreads in the step loop.
// ---------------------------------------------------------------------------
__global__ __launch_bounds__(256, 1) void lstm_persist(
    const u16* __restrict__ WcF, const u16* __restrict__ WcB,
    const u16* __restrict__ xb,
    const float* __restrict__ bF, const float* __restrict__ bB,
    u16* __restrict__ hs, float* __restrict__ out_tail, int* flags)
{
  extern __shared__ __align__(16) u16 Bs[];   // [dir][NSL][2][64][8]

  // one-time: clear stale lines (hs poison / previous call) from L1/L2
  __builtin_amdgcn_fence(__ATOMIC_ACQUIRE, "agent");

  const int nb = blockIdx.x;
  const int n0 = nb * 32;
  const int jbase = nb * 8;
  const int tid = threadIdx.x;
  const int w = tid >> 6, lane = tid & 63;
  const int r = lane & 15, q = lane >> 4, rq = r >> 2;
  int* __restrict__ fl = flags + w * NBLK;

  // stage BOTH B panels into LDS: chunk c -> [dir][ks][nt][lane] 16B
  for (int c = tid; c < 2 * NSL * 128; c += 256) {
    int dir = (c >= NSL * 128);
    int rem = c - dir * NSL * 128;
    int ks  = rem >> 7;
    int r2  = rem & 127;
    int nt  = r2 >> 6, l2 = r2 & 63;
    const u16* Wc = dir ? WcB : WcF;
    *(short8*)&Bs[(size_t)c * 8] =
        *(const short8*)(Wc + (size_t)(n0 + nt*16 + (l2 & 15)) * KC + ks*32 + (l2 >> 4)*8);
  }

  float biaF[2][4], biaB[2][4];
  #pragma unroll
  for (int nt = 0; nt < 2; ++nt)
    #pragma unroll
    for (int g = 0; g < 4; ++g) {
      biaF[nt][g] = bF[g * HID + jbase + 2*rq + nt];
      biaB[nt][g] = bB[g * HID + jbase + 2*rq + nt];
    }

  float cF[2][4], cB[2][4];
  #pragma unroll
  for (int nt = 0; nt < 2; ++nt)
    #pragma unroll
    for (int rg = 0; rg < 4; ++rg) { cF[nt][rg] = 0.f; cB[nt][rg] = 0.f; }

  const int row_a = w * 16 + r;

  // B-fragment accessor offset helper (byte-free, in u16 units)
  #define BSF(dir, ks, nt) (*(const short8*)&Bs[((size_t)((((dir)*NSL + (ks))*2 + (nt))*64 + lane))*8])

  // x prefetch for s=0 (F reads t=0, B reads t=255)
  short8 xf[8], xg[8];
  ld_chunk(xf, xb + ((size_t)0           * BATCH + row_a) * INP, 0, q);
  ld_chunk(xg, xb + ((size_t)(T_SEQ - 1) * BATCH + row_a) * INP, 0, q);

  __syncthreads();   // Bs staging complete (only barrier outside prologue)

  f32x4 aF[2], aB[2];
  aF[0] = (f32x4)(0.f); aF[1] = (f32x4)(0.f);
  aB[0] = (f32x4)(0.f); aB[1] = (f32x4)(0.f);
  #pragma unroll
  for (int kx = 0; kx < 8; ++kx) {
    int ks = 32 + kx;
    aF[0] = MFMA16(xf[kx], BSF(0, ks, 0), aF[0]);
    aF[1] = MFMA16(xf[kx], BSF(0, ks, 1), aF[1]);
    aB[0] = MFMA16(xg[kx], BSF(1, ks, 0), aB[0]);
    aB[1] = MFMA16(xg[kx], BSF(1, ks, 1), aB[1]);
  }

  short8 mF0[8], mB0[8], mF1[8], mB1[8];

  for (int s = 0; s < T_SEQ; ++s) {
    const int ttF = s, ttB = T_SEQ - 1 - s;

    if (s > 0) {
      const u16* __restrict__ arF = hs + ((size_t)(s - 1)     * BATCH + row_a) * 2048;
      const u16* __restrict__ arB = hs + ((size_t)(T_SEQ - s) * BATCH + row_a) * 2048 + HID;
      // deep pipeline: 4 chunks in flight, F/B interleaved
      ld_chunk(mF0, arF, 0,  q);
      ld_chunk(mB0, arB, 0,  q);
      ld_chunk(mF1, arF, 8,  q);
      ld_chunk(mB1, arB, 8,  q);
      #pragma unroll
      for (int i = 0; i < 8; ++i) {
        aF[0] = MFMA16(mF0[i], BSF(0, i, 0), aF[0]);
        aF[1] = MFMA16(mF0[i], BSF(0, i, 1), aF[1]);
      }
      ld_chunk(xf, arF, 16, q);
      #pragma unroll
      for (int i = 0; i < 8; ++i) {
        aB[0] = MFMA16(mB0[i], BSF(1, i, 0), aB[0]);
        aB[1] = MFMA16(mB0[i], BSF(1, i, 1), aB[1]);
      }
      ld_chunk(xg, arB, 16, q);
      #pragma unroll
      for (int i = 0; i < 8; ++i) {
        aF[0] = MFMA16(mF1[i], BSF(0, 8 + i, 0), aF[0]);
        aF[1] = MFMA16(mF1[i], BSF(0, 8 + i, 1), aF[1]);
      }
      ld_chunk(mF0, arF, 24, q);
      #pragma unroll
      for (int i = 0; i < 8; ++i) {
        aB[0] = MFMA16(mB1[i], BSF(1, 8 + i, 0), aB[0]);
        aB[1] = MFMA16(mB1[i], BSF(1, 8 + i, 1), aB[1]);
      }
      ld_chunk(mB0, arB, 24, q);
      #pragma unroll
      for (int i = 0; i < 8; ++i) {
        aF[0] = MFMA16(xf[i], BSF(0, 16 + i, 0), aF[0]);
        aF[1] = MFMA16(xf[i], BSF(0, 16 + i, 1), aF[1]);
        aB[0] = MFMA16(xg[i], BSF(1, 16 + i, 0), aB[0]);
        aB[1] = MFMA16(xg[i], BSF(1, 16 + i, 1), aB[1]);
      }
      #pragma unroll
      for (int i = 0; i < 8; ++i) {
        aF[0] = MFMA16(mF0[i], BSF(0, 24 + i, 0), aF[0]);
        aF[1] = MFMA16(mF0[i], BSF(0, 24 + i, 1), aF[1]);
        aB[0] = MFMA16(mB0[i], BSF(1, 24 + i, 0), aB[0]);
        aB[1] = MFMA16(mB0[i], BSF(1, 24 + i, 1), aB[1]);
      }
    }

    // ---- cell update, both dirs (DPP gate gather; writer lanes r&3==0) ----
    float hnF[2][4], hnB[2][4];
    u32 hwF[4], hwB[4];
    #pragma unroll
    for (int nt = 0; nt < 2; ++nt) {
      #pragma unroll
      for (int rg = 0; rg < 4; ++rg) {
        float v  = aF[nt][rg];
        float x1 = qperm<QP_XOR1>(v);
        float x2 = qperm<QP_XOR2>(v);
        float x3 = qperm<QP_XOR2>(x1);
        float cn = sigm(x1 + biaF[nt][1]) * cF[nt][rg] + sigm(v + biaF[nt][0]) * tanhf_(x3 + biaF[nt][3]);
        float hn = sigm(x2 + biaF[nt][2]) * tanhf_(cn);
        cF[nt][rg] = cn; hnF[nt][rg] = hn;
        v  = aB[nt][rg];
        x1 = qperm<QP_XOR1>(v);
        x2 = qperm<QP_XOR2>(v);
        x3 = qperm<QP_XOR2>(x1);
        cn = sigm(x1 + biaB[nt][1]) * cB[nt][rg] + sigm(v + biaB[nt][0]) * tanhf_(x3 + biaB[nt][3]);
        hn = sigm(x2 + biaB[nt][2]) * tanhf_(cn);
        cB[nt][rg] = cn; hnB[nt][rg] = hn;
      }
    }
    #pragma unroll
    for (int rg = 0; rg < 4; ++rg) {
      hwF[rg] = (u32)f2bf(hnF[0][rg]) | ((u32)f2bf(hnF[1][rg]) << 16);
      hwB[rg] = (u32)f2bf(hnB[0][rg]) | ((u32)f2bf(hnB[1][rg]) << 16);
    }
    // packed write-through h stores: cols (jbase+2rq, +1), rows w*16+q*4+rg
    if ((r & 3) == 0) {
      #pragma unroll
      for (int rg = 0; rg < 4; ++rg) {
        int row = w * 16 + q * 4 + rg;
        st_u32_wt((u32*)(hs + ((size_t)ttF * BATCH + row) * 2048 + jbase + 2*rq),       hwF[rg]);
        st_u32_wt((u32*)(hs + ((size_t)ttB * BATCH + row) * 2048 + HID + jbase + 2*rq), hwB[rg]);
      }
    }

    if (s < T_SEQ - 1) {
      asm volatile("s_waitcnt vmcnt(0)" ::: "memory");   // drain h stores to IC
      if (lane == 0) st_u32_wt((u32*)(fl + nb), (u32)(s + 1));
      // next step's x loads land during the poll
      ld_chunk(xf, xb + ((size_t)(ttF + 1) * BATCH + row_a) * INP, 0, q);
      ld_chunk(xg, xb + ((size_t)(ttB - 1) * BATCH + row_a) * INP, 0, q);
      {
        const int tgt = s + 1;
        while (true) {
          int f0 = __hip_atomic_load(fl + 2 * lane,     __ATOMIC_RELAXED, __HIP_MEMORY_SCOPE_AGENT);
          int f1 = __hip_atomic_load(fl + 2 * lane + 1, __ATOMIC_RELAXED, __HIP_MEMORY_SCOPE_AGENT);
          if (__all((f0 >= tgt) && (f1 >= tgt))) break;
        }
      }
      // start next step: x-part MFMAs (h addresses are write-once, flag-gated)
      aF[0] = (f32x4)(0.f); aF[1] = (f32x4)(0.f);
      aB[0] = (f32x4)(0.f); aB[1] = (f32x4)(0.f);
      #pragma unroll
      for (int kx = 0; kx < 8; ++kx) {
        int ks = 32 + kx;
        aF[0] = MFMA16(xf[kx], BSF(0, ks, 0), aF[0]);
        aF[1] = MFMA16(xf[kx], BSF(0, ks, 1), aF[1]);
        aB[0] = MFMA16(xg[kx], BSF(1, ks, 0), aB[0]);
        aB[1] = MFMA16(xg[kx], BSF(1, ks, 1), aB[1]);
      }
    } else {
      // final states: ((hF,hB),(cF,cB)) flat after outputs
      if ((r & 3) == 0) {
        #pragma unroll
        for (int nt = 0; nt < 2; ++nt)
          #pragma unroll
          for (int rg = 0; rg < 4; ++rg) {
            int row = w * 16 + q * 4 + rg;
            int j   = jbase + 2*rq + nt;
            st_f32_wt(out_tail + 0 * (BATCH * HID) + (size_t)row * HID + j, hnF[nt][rg]);
            st_f32_wt(out_tail + 1 * (BATCH * HID) + (size_t)row * HID + j, hnB[nt][rg]);
            st_f32_wt(out_tail + 2 * (BATCH * HID) + (size_t)row * HID + j, cF[nt][rg]);
            st_f32_wt(out_tail + 3 * (BATCH * HID) + (size_t)row * HID + j, cB[nt][rg]);
          }
      }
    }
  }
  #undef BSF
}

// ---------------------------------------------------------------------------
// Final FC: out[16384][1024] = hs[16384][2048] @ WfcT^T + b_fc, f32 out.
// ---------------------------------------------------------------------------
__global__ __launch_bounds__(256) void fc_kernel(
    const u16* __restrict__ hs, const u16* __restrict__ WfcT,
    const float* __restrict__ bfc, float* __restrict__ out)
{
  const int m0 = blockIdx.x * 128, n0 = blockIdx.y * 128;
  __shared__ __align__(16) u16 As[128 * 32];
  __shared__ __align__(16) u16 Bs[128 * 32];
  const int tid = threadIdx.x;
  const int w = tid >> 6, lane = tid & 63;
  const int r = lane & 15, q = lane >> 4;
  const int wy = w >> 1, wx = w & 1;

  f32x4 acc[4][4];
  #pragma unroll
  for (int a = 0; a < 4; ++a)
    #pragma unroll
    for (int b = 0; b < 4; ++b) acc[a][b] = (f32x4)(0.f);

  const int lr = tid >> 1, lk = (tid & 1) * 16;

  for (int k0 = 0; k0 < 2048; k0 += 32) {
    __syncthreads();
    *(short8*)&As[lr * 32 + lk]     = *(const short8*)(hs   + (size_t)(m0 + lr) * 2048 + k0 + lk);
    *(short8*)&As[lr * 32 + lk + 8] = *(const short8*)(hs   + (size_t)(m0 + lr) * 2048 + k0 + lk + 8);
    *(short8*)&Bs[lr * 32 + lk]     = *(const short8*)(WfcT + (size_t)(n0 + lr) * 2048 + k0 + lk);
    *(short8*)&Bs[lr * 32 + lk + 8] = *(const short8*)(WfcT + (size_t)(n0 + lr) * 2048 + k0 + lk + 8);
    __syncthreads();

    short8 af[4], bf[4];
    #pragma unroll
    for (int mt = 0; mt < 4; ++mt)
      af[mt] = *(const short8*)&As[(wy * 64 + mt * 16 + r) * 32 + q * 8];
    #pragma unroll
    for (int nt = 0; nt < 4; ++nt)
      bf[nt] = *(const short8*)&Bs[(wx * 64 + nt * 16 + r) * 32 + q * 8];
    #pragma unroll
    for (int mt = 0; mt < 4; ++mt)
      #pragma unroll
      for (int nt = 0; nt < 4; ++nt)
        acc[mt][nt] = __builtin_amdgcn_mfma_f32_16x16x32_bf16(af[mt], bf[nt], acc[mt][nt], 0, 0, 0);
  }

  #pragma unroll
  for (int mt = 0; mt < 4; ++mt)
    #pragma unroll
    for (int nt = 0; nt < 4; ++nt)
      #pragma unroll
      for (int reg = 0; reg < 4; ++reg) {
        int m = m0 + wy * 64 + mt * 16 + q * 4 + reg;
        int n = n0 + wx * 64 + nt * 16 + r;
        out[(size_t)m * OUTD + n] = acc[mt][nt][reg] + bfc[n];
      }
}

// ---------------------------------------------------------------------------
extern "C" void kernel_launch(void* const* d_in, const int* in_sizes, int n_in,
                              void* d_out, int out_size, void* d_ws, size_t ws_size,
                              hipStream_t stream)
{
  const float* x   = (const float*)d_in[0];
  const float* WxF = (const float*)d_in[1];
  const float* WhF = (const float*)d_in[2];
  const float* bF  = (const float*)d_in[3];
  const float* WxB = (const float*)d_in[4];
  const float* WhB = (const float*)d_in[5];
  const float* bB  = (const float*)d_in[6];
  const float* Wfc = (const float*)d_in[7];
  const float* bfc = (const float*)d_in[8];
  float* out = (float*)d_out;

  char* ws = (char*)d_ws;
  u16*  WcF   = (u16*)(ws + 0);          // 10485760
  u16*  WcB   = (u16*)(ws + 10485760);   // 10485760
  u16*  WfcT  = (u16*)(ws + 20971520);   // 4194304
  u16*  xb    = (u16*)(ws + 25165824);   // 8388608
  u16*  hs    = (u16*)(ws + 34603008);   // 67108864
  int*  flags = (int*)(ws + 101711872);  // 2KB (4 waves x 128 blocks)

  hipMemsetAsync(flags, 0, 2048, stream);   // barrier flags

  hipFuncSetAttribute((const void*)lstm_persist,
                      hipFuncAttributeMaxDynamicSharedMemorySize, LDSB);

  build_wc <<<dim3(KC/64, HID/64, 8), 256, 0, stream>>>(WhF, WxF, WhB, WxB, WcF, WcB);
  build_wfc<<<dim3(2048/64, OUTD/64), 256, 0, stream>>>(Wfc, WfcT);
  conv_x   <<<(T_SEQ*BATCH*INP)/4/256, 256, 0, stream>>>(x, xb, T_SEQ*BATCH*INP);

  lstm_persist<<<NBLK, 256, LDSB, stream>>>(WcF, WcB, xb, bF, bB,
                                            hs, out + 16777216, flags);

  fc_kernel<<<dim3(16384/128, OUTD/128), 256, 0, stream>>>(hs, WfcT, bfc, out);
}

// Round 8
// 3376.300 us; speedup vs baseline: 1.2190x; 1.2190x over previous
//
#include <hip/hip_runtime.h>

using short8 = __attribute__((ext_vector_type(8))) short;
using f32x4  = __attribute__((ext_vector_type(4))) float;

typedef unsigned short u16;
typedef unsigned int   u32;

#define T_SEQ 256
#define BATCH 64
#define INP   256
#define HID   1024
#define GDIM  4096
#define KC    1280   // HID + INP
#define OUTD  1024

#define NSL   40     // K slices of 32 (32 h + 8 x)
#define NBLK  256
#define LDSB  98304  // request 96KB -> exactly 1 block/CU (panel uses 80KB)

#define MFMA16(a,b,c) __builtin_amdgcn_mfma_f32_16x16x32_bf16(a,b,c,0,0,0)

__device__ __forceinline__ u16 f2bf(float f){
  union { float f; u32 u; } v; v.f = f;
  u32 r = v.u + 0x7fffu + ((v.u >> 16) & 1u);
  return (u16)(r >> 16);
}
__device__ __forceinline__ float sigm(float x){ return 1.f/(1.f+__expf(-x)); }
__device__ __forceinline__ float tanhf_(float x){ return 1.f - 2.f/(__expf(2.f*x)+1.f); }

__device__ __forceinline__ void st_u32_wt(u32* p, u32 v){
  asm volatile("global_store_dword %0, %1, off sc0 sc1" :: "v"(p), "v"(v) : "memory");
}
__device__ __forceinline__ void st_f32_wt(float* p, float v){
  asm volatile("global_store_dword %0, %1, off sc0 sc1" :: "v"(p), "v"(v) : "memory");
}

// quad-perm DPP: gates of one h-col live in one quad (n = jl*4 + gate)
template<int CTRL>
__device__ __forceinline__ float qperm(float v){
  union { float f; int i; } u; u.f = v;
  u.i = __builtin_amdgcn_mov_dpp(u.i, CTRL, 0xf, 0xf, true);
  return u.f;
}
#define QP_XOR1 177   // quad_perm [1,0,3,2]
#define QP_XOR2 78    // quad_perm [2,3,0,1]

// ---------------------------------------------------------------------------
// Prep: combined recurrent weights, bf16.
// Block nb owns, per dir, gate-cols [nb*16, nb*16+16):
//   n_global = (j>>2)*16 + (j&3)*4 + gate   (j = h-col; quad = 4 gates of j)
// Rows: k<1024 -> Wh[k][gate*1024+j], k>=1024 -> Wx[k-1024][gate*1024+j].
// ---------------------------------------------------------------------------
__global__ void build_wc(const float* __restrict__ WhF, const float* __restrict__ WxF,
                         const float* __restrict__ WhB, const float* __restrict__ WxB,
                         u16* __restrict__ WcF, u16* __restrict__ WcB)
{
  const int z = blockIdx.z; const int dir = z >> 2, gate = z & 3;
  const float* Wh = dir ? WhB : WhF;
  const float* Wx = dir ? WxB : WxF;
  u16* Wc = dir ? WcB : WcF;
  const int k0 = blockIdx.x * 64, j0 = blockIdx.y * 64;
  __shared__ float tile[64][65];
  const int t = threadIdx.x;
  #pragma unroll
  for (int i = 0; i < 16; ++i) {
    int idx = i*256 + t; int kr = idx >> 6, jc = idx & 63;
    int k = k0 + kr;
    float v = (k < HID) ? Wh[(size_t)k*GDIM + gate*HID + j0 + jc]
                        : Wx[(size_t)(k-HID)*GDIM + gate*HID + j0 + jc];
    tile[kr][jc] = v;
  }
  __syncthreads();
  #pragma unroll
  for (int i = 0; i < 16; ++i) {
    int idx = i*256 + t; int jc = idx >> 6, kr = idx & 63;
    int j  = j0 + jc;
    int n  = (j >> 2)*16 + (j & 3)*4 + gate;
    Wc[(size_t)n*KC + k0 + kr] = f2bf(tile[kr][jc]);
  }
}

__global__ void build_wfc(const float* __restrict__ Wfc, u16* __restrict__ WfcT)
{
  const int k0 = blockIdx.x * 64;
  const int n0 = blockIdx.y * 64;
  __shared__ float tile[64][65];
  const int t = threadIdx.x;
  #pragma unroll
  for (int i = 0; i < 16; ++i) {
    int idx = i*256 + t; int kr = idx >> 6, nc = idx & 63;
    tile[kr][nc] = Wfc[(size_t)(k0+kr)*OUTD + n0 + nc];
  }
  __syncthreads();
  #pragma unroll
  for (int i = 0; i < 16; ++i) {
    int idx = i*256 + t; int nc = idx >> 6, kr = idx & 63;
    WfcT[(size_t)(n0+nc)*2048 + k0 + kr] = f2bf(tile[kr][nc]);
  }
}

__global__ void conv_x(const float* __restrict__ x, u16* __restrict__ xb, int n)
{
  int i = (blockIdx.x * blockDim.x + threadIdx.x) * 4;
  if (i < n) {
    float4 v = *(const float4*)(x + i);
    u32 lo = (u32)f2bf(v.x) | ((u32)f2bf(v.y) << 16);
    u32 hi = (u32)f2bf(v.z) | ((u32)f2bf(v.w) << 16);
    *(uint2*)(xb + i) = make_uint2(lo, hi);
  }
}

// ---------------------------------------------------------------------------
// Persistent bidirectional LSTM, direction-fused with STAGGERED barriers.
// 256 blocks; block nb owns 4 h-cols of F and 4 h-cols of B. Per step:
// F phase (poll F flags, 40 MFMAs, update, store, flag) then B phase.
// Flag loads for each phase are prefetched during the opposite phase, so
// the poll normally completes with zero wait. Per-wave flags (wave w owns
// batch rows 16w..16w+15); no __syncthreads in the step loop.
// ---------------------------------------------------------------------------
__global__ __launch_bounds__(256, 1) void lstm_persist(
    const u16* __restrict__ WcF, const u16* __restrict__ WcB,
    const u16* __restrict__ xb,
    const float* __restrict__ bF, const float* __restrict__ bB,
    u16* __restrict__ hs, float* __restrict__ out_tail, int* flags)
{
  extern __shared__ __align__(16) u16 Bs[];   // [dir][NSL][64 lanes][8 u16]

  __builtin_amdgcn_fence(__ATOMIC_ACQUIRE, "agent");

  const int nb  = blockIdx.x;
  const int tid = threadIdx.x;
  const int w   = tid >> 6, lane = tid & 63;
  const int l15 = lane & 15, q = lane >> 4;
  const int row_a = w * 16 + l15;          // A-frag row; D rows = w*16+q*4+rg
  const int jcol  = nb * 4 + (l15 >> 2);   // this lane's h-col (per dir)

  // stage both B panels: [dir][ks][lane] 16B fragments
  for (int c = tid; c < 2 * NSL * 64; c += 256) {
    int dir = c >= NSL * 64;
    int rem = c - dir * NSL * 64;
    int ks  = rem >> 6, l = rem & 63;
    const u16* Wsrc = dir ? WcB : WcF;
    *(short8*)&Bs[(size_t)c * 8] =
        *(const short8*)(Wsrc + (size_t)(nb*16 + (l & 15)) * KC + ks*32 + (l >> 4)*8);
  }
  #define BSF(dir, ks) (*(const short8*)&Bs[((size_t)(((dir)*NSL + (ks))*64 + lane))*8])

  float biaF[4], biaB[4];
  #pragma unroll
  for (int g = 0; g < 4; ++g) {
    biaF[g] = bF[g * HID + jcol];
    biaB[g] = bB[g * HID + jcol];
  }
  float cFr[4] = {0.f,0.f,0.f,0.f};
  float cBr[4] = {0.f,0.f,0.f,0.f};

  // per-wave flag arrays: flags[(dir*4 + w)*NBLK + block]
  int* __restrict__ flF = flags + (0*4 + w) * NBLK;
  int* __restrict__ flB = flags + (1*4 + w) * NBLK;
  int pfF[4] = {0,0,0,0}, pfB[4] = {0,0,0,0};

  __syncthreads();   // panels staged

  // ---- one phase: loads -> MFMAs -> cell update -> packed WT stores ----
  auto phase = [&](int dir, int tt, const u16* ar, float* creg, const float* bia,
                   const int* fl_other, int* pf_other, bool final_) {
    short8 hA[32], xa[8];
    if (ar) {
      #pragma unroll
      for (int i = 0; i < 32; ++i) hA[i] = *(const short8*)(ar + i*32 + q*8);
    }
    const u16* xr = xb + ((size_t)tt * BATCH + row_a) * INP;
    #pragma unroll
    for (int i = 0; i < 8; ++i) xa[i] = *(const short8*)(xr + i*32 + q*8);
    if (fl_other) {   // prefetch opposite-phase flags (latency hides here)
      #pragma unroll
      for (int i = 0; i < 4; ++i)
        pf_other[i] = __hip_atomic_load(fl_other + lane + i*64,
                                        __ATOMIC_RELAXED, __HIP_MEMORY_SCOPE_AGENT);
    }
    f32x4 acc = (f32x4)(0.f);
    if (ar) {
      #pragma unroll
      for (int i = 0; i < 32; ++i) acc = MFMA16(hA[i], BSF(dir, i), acc);
    }
    #pragma unroll
    for (int i = 0; i < 8; ++i) acc = MFMA16(xa[i], BSF(dir, 32 + i), acc);

    // cell update: quad holds gates i,f,o,cg of h-col jcol
    float hn4[4];
    #pragma unroll
    for (int rg = 0; rg < 4; ++rg) {
      float v  = acc[rg];
      float x1 = qperm<QP_XOR1>(v);
      float x2 = qperm<QP_XOR2>(v);
      float x3 = qperm<QP_XOR2>(x1);
      float cn = sigm(x1 + bia[1]) * creg[rg] + sigm(v + bia[0]) * tanhf_(x3 + bia[3]);
      float hn = sigm(x2 + bia[2]) * tanhf_(cn);
      creg[rg] = cn; hn4[rg] = hn;
    }
    // pack col pair via lane^4 swizzle; u32 write-through stores
    u16* hrow = hs + (size_t)tt * BATCH * 2048 + dir * HID + nb * 4;
    #pragma unroll
    for (int rg = 0; rg < 4; ++rg) {
      u32 v32 = (u32)f2bf(hn4[rg]);
      u32 pr  = (u32)__builtin_amdgcn_ds_swizzle((int)v32, 0x101F);  // lane^4
      if ((lane & 7) == 0) {
        int row = w * 16 + q * 4 + rg;
        st_u32_wt((u32*)(hrow + (size_t)row * 2048 + (l15 >> 2)), v32 | (pr << 16));
      }
    }
    if (final_ && (lane & 3) == 0) {
      float* ot = out_tail + dir * (BATCH * HID);
      #pragma unroll
      for (int rg = 0; rg < 4; ++rg) {
        int row = w * 16 + q * 4 + rg;
        st_f32_wt(ot + (size_t)row * HID + jcol, hn4[rg]);
        st_f32_wt(ot + 2 * (BATCH * HID) + (size_t)row * HID + jcol, cFr == creg ? cFr[rg] : cBr[rg]);
      }
    }
  };

  auto poll_wait = [&](const int* fl, int* pf, int tgt) {
    while (true) {
      int ok = (pf[0] >= tgt) && (pf[1] >= tgt) && (pf[2] >= tgt) && (pf[3] >= tgt);
      if (__all(ok)) break;
      #pragma unroll
      for (int i = 0; i < 4; ++i)
        pf[i] = __hip_atomic_load(fl + lane + i*64,
                                  __ATOMIC_RELAXED, __HIP_MEMORY_SCOPE_AGENT);
    }
  };

  // ---------------- prologue: s = 0 (x-only) ----------------
  phase(0, 0, nullptr, cFr, biaF, nullptr, nullptr, false);
  asm volatile("s_waitcnt vmcnt(0)" ::: "memory");
  if (lane == 0) st_u32_wt((u32*)(flF + nb), 1u);
  phase(1, T_SEQ - 1, nullptr, cBr, biaB, flF, pfF, false);
  asm volatile("s_waitcnt vmcnt(0)" ::: "memory");
  if (lane == 0) st_u32_wt((u32*)(flB + nb), 1u);

  // ---------------- steps 1..255 ----------------
  for (int s = 1; s < T_SEQ; ++s) {
    const bool last = (s == T_SEQ - 1);
    // F phase: needs hF(s-1) at hs[s-1]
    poll_wait(flF, pfF, s);
    {
      const u16* ar = hs + ((size_t)(s - 1) * BATCH + row_a) * 2048;
      phase(0, s, ar, cFr, biaF, flB, pfB, last);
    }
    asm volatile("s_waitcnt vmcnt(0)" ::: "memory");
    if (lane == 0) st_u32_wt((u32*)(flF + nb), (u32)(s + 1));

    // B phase: needs hB(s-1) at hs[256-s]
    poll_wait(flB, pfB, s);
    {
      const u16* ar = hs + ((size_t)(T_SEQ - s) * BATCH + row_a) * 2048 + HID;
      phase(1, T_SEQ - 1 - s, ar, cBr, biaB, flF, pfF, last);
    }
    asm volatile("s_waitcnt vmcnt(0)" ::: "memory");
    if (lane == 0) st_u32_wt((u32*)(flB + nb), (u32)(s + 1));
  }
  #undef BSF
}

// ---------------------------------------------------------------------------
// Final FC: out[16384][1024] = hs[16384][2048] @ WfcT^T + b_fc, f32 out.
// ---------------------------------------------------------------------------
__global__ __launch_bounds__(256) void fc_kernel(
    const u16* __restrict__ hs, const u16* __restrict__ WfcT,
    const float* __restrict__ bfc, float* __restrict__ out)
{
  const int m0 = blockIdx.x * 128, n0 = blockIdx.y * 128;
  __shared__ __align__(16) u16 As[128 * 32];
  __shared__ __align__(16) u16 Bs[128 * 32];
  const int tid = threadIdx.x;
  const int w = tid >> 6, lane = tid & 63;
  const int r = lane & 15, q = lane >> 4;
  const int wy = w >> 1, wx = w & 1;

  f32x4 acc[4][4];
  #pragma unroll
  for (int a = 0; a < 4; ++a)
    #pragma unroll
    for (int b = 0; b < 4; ++b) acc[a][b] = (f32x4)(0.f);

  const int lr = tid >> 1, lk = (tid & 1) * 16;

  for (int k0 = 0; k0 < 2048; k0 += 32) {
    __syncthreads();
    *(short8*)&As[lr * 32 + lk]     = *(const short8*)(hs   + (size_t)(m0 + lr) * 2048 + k0 + lk);
    *(short8*)&As[lr * 32 + lk + 8] = *(const short8*)(hs   + (size_t)(m0 + lr) * 2048 + k0 + lk + 8);
    *(short8*)&Bs[lr * 32 + lk]     = *(const short8*)(WfcT + (size_t)(n0 + lr) * 2048 + k0 + lk);
    *(short8*)&Bs[lr * 32 + lk + 8] = *(const short8*)(WfcT + (size_t)(n0 + lr) * 2048 + k0 + lk + 8);
    __syncthreads();

    short8 af[4], bf[4];
    #pragma unroll
    for (int mt = 0; mt < 4; ++mt)
      af[mt] = *(const short8*)&As[(wy * 64 + mt * 16 + r) * 32 + q * 8];
    #pragma unroll
    for (int nt = 0; nt < 4; ++nt)
      bf[nt] = *(const short8*)&Bs[(wx * 64 + nt * 16 + r) * 32 + q * 8];
    #pragma unroll
    for (int mt = 0; mt < 4; ++mt)
      #pragma unroll
      for (int nt = 0; nt < 4; ++nt)
        acc[mt][nt] = __builtin_amdgcn_mfma_f32_16x16x32_bf16(af[mt], bf[nt], acc[mt][nt], 0, 0, 0);
  }

  #pragma unroll
  for (int mt = 0; mt < 4; ++mt)
    #pragma unroll
    for (int nt = 0; nt < 4; ++nt)
      #pragma unroll
      for (int reg = 0; reg < 4; ++reg) {
        int m = m0 + wy * 64 + mt * 16 + q * 4 + reg;
        int n = n0 + wx * 64 + nt * 16 + r;
        out[(size_t)m * OUTD + n] = acc[mt][nt][reg] + bfc[n];
      }
}

// ---------------------------------------------------------------------------
extern "C" void kernel_launch(void* const* d_in, const int* in_sizes, int n_in,
                              void* d_out, int out_size, void* d_ws, size_t ws_size,
                              hipStream_t stream)
{
  const float* x   = (const float*)d_in[0];
  const float* WxF = (const float*)d_in[1];
  const float* WhF = (const float*)d_in[2];
  const float* bF  = (const float*)d_in[3];
  const float* WxB = (const float*)d_in[4];
  const float* WhB = (const float*)d_in[5];
  const float* bB  = (const float*)d_in[6];
  const float* Wfc = (const float*)d_in[7];
  const float* bfc = (const float*)d_in[8];
  float* out = (float*)d_out;

  char* ws = (char*)d_ws;
  u16*  WcF   = (u16*)(ws + 0);          // 10485760
  u16*  WcB   = (u16*)(ws + 10485760);   // 10485760
  u16*  WfcT  = (u16*)(ws + 20971520);   // 4194304
  u16*  xb    = (u16*)(ws + 25165824);   // 8388608
  u16*  hs    = (u16*)(ws + 34603008);   // 67108864
  int*  flags = (int*)(ws + 101711872);  // 8KB (2 dirs x 4 waves x 256)

  hipMemsetAsync(flags, 0, 8192, stream);

  hipFuncSetAttribute((const void*)lstm_persist,
                      hipFuncAttributeMaxDynamicSharedMemorySize, LDSB);

  build_wc <<<dim3(KC/64, HID/64, 8), 256, 0, stream>>>(WhF, WxF, WhB, WxB, WcF, WcB);
  build_wfc<<<dim3(2048/64, OUTD/64), 256, 0, stream>>>(Wfc, WfcT);
  conv_x   <<<(T_SEQ*BATCH*INP)/4/256, 256, 0, stream>>>(x, xb, T_SEQ*BATCH*INP);

  lstm_persist<<<NBLK, 256, LDSB, stream>>>(WcF, WcB, xb, bF, bB,
                                            hs, out + 16777216, flags);

  fc_kernel<<<dim3(16384/128, OUTD/128), 256, 0, stream>>>(hs, WfcT, bfc, out);
}

// Round 9
// 2741.492 us; speedup vs baseline: 1.5012x; 1.2316x over previous
//
#include <hip/hip_runtime.h>

using short8 = __attribute__((ext_vector_type(8))) short;
using f32x4  = __attribute__((ext_vector_type(4))) float;

typedef unsigned short u16;
typedef unsigned int   u32;

#define T_SEQ 256
#define BATCH 64
#define INP   256
#define HID   1024
#define GDIM  4096
#define KC    1280   // HID + INP
#define OUTD  1024

#define NSL   40     // K slices of 32 (32 h + 8 x)
#define NBLK  256
#define DBLK  128    // blocks per direction
#define LDSB  (NSL * 2 * 64 * 8 * 2)   // 81920 bytes dynamic LDS

#define MFMA16(a,b,c) __builtin_amdgcn_mfma_f32_16x16x32_bf16(a,b,c,0,0,0)

__device__ __forceinline__ u16 f2bf(float f){
  union { float f; u32 u; } v; v.f = f;
  u32 r = v.u + 0x7fffu + ((v.u >> 16) & 1u);
  return (u16)(r >> 16);
}
__device__ __forceinline__ float sigm(float x){ return 1.f/(1.f+__expf(-x)); }
__device__ __forceinline__ float tanhf_(float x){ return 1.f - 2.f/(__expf(2.f*x)+1.f); }

// agent-scope (device-coherent, IC-resident) store/load — compiler emits sc1
__device__ __forceinline__ void ag_st_u32(u32* p, u32 v){
  __hip_atomic_store(p, v, __ATOMIC_RELAXED, __HIP_MEMORY_SCOPE_AGENT);
}
__device__ __forceinline__ int ag_ld_i32(const int* p){
  return __hip_atomic_load(p, __ATOMIC_RELAXED, __HIP_MEMORY_SCOPE_AGENT);
}

// quad-perm DPP: 4 gates of one h-col live in one lane-quad
template<int CTRL>
__device__ __forceinline__ float qperm(float v){
  union { float f; int i; } u; u.f = v;
  u.i = __builtin_amdgcn_mov_dpp(u.i, CTRL, 0xf, 0xf, true);
  return u.f;
}
#define QP_XOR1 177   // quad_perm [1,0,3,2]
#define QP_XOR2 78    // quad_perm [2,3,0,1]

// ---------------------------------------------------------------------------
// Prep: combined recurrent weights, bf16, block-permuted column order.
// Block nb owns gate-cols [nb*32, nb*32+32); n = nb*32 + nt*16 + rq*4 + gate,
// h-col j = nb*8 + 2*rq + nt. Rows k<1024 -> Wh, k>=1024 -> Wx.
// ---------------------------------------------------------------------------
__global__ void build_wc(const float* __restrict__ WhF, const float* __restrict__ WxF,
                         const float* __restrict__ WhB, const float* __restrict__ WxB,
                         u16* __restrict__ WcF, u16* __restrict__ WcB)
{
  const int z = blockIdx.z; const int dir = z >> 2, gate = z & 3;
  const float* Wh = dir ? WhB : WhF;
  const float* Wx = dir ? WxB : WxF;
  u16* Wc = dir ? WcB : WcF;
  const int k0 = blockIdx.x * 64, j0 = blockIdx.y * 64;
  __shared__ float tile[64][65];
  const int t = threadIdx.x;
  #pragma unroll
  for (int i = 0; i < 16; ++i) {
    int idx = i*256 + t; int kr = idx >> 6, jc = idx & 63;
    int k = k0 + kr;
    float v = (k < HID) ? Wh[(size_t)k*GDIM + gate*HID + j0 + jc]
                        : Wx[(size_t)(k-HID)*GDIM + gate*HID + j0 + jc];
    tile[kr][jc] = v;
  }
  __syncthreads();
  #pragma unroll
  for (int i = 0; i < 16; ++i) {
    int idx = i*256 + t; int jc = idx >> 6, kr = idx & 63;
    int j  = j0 + jc;
    int nb = j >> 3, jl = j & 7;
    int nt = jl & 1, rq = jl >> 1;
    int n  = nb*32 + nt*16 + rq*4 + gate;
    Wc[(size_t)n*KC + k0 + kr] = f2bf(tile[kr][jc]);
  }
}

__global__ void build_wfc(const float* __restrict__ Wfc, u16* __restrict__ WfcT)
{
  const int k0 = blockIdx.x * 64;
  const int n0 = blockIdx.y * 64;
  __shared__ float tile[64][65];
  const int t = threadIdx.x;
  #pragma unroll
  for (int i = 0; i < 16; ++i) {
    int idx = i*256 + t; int kr = idx >> 6, nc = idx & 63;
    tile[kr][nc] = Wfc[(size_t)(k0+kr)*OUTD + n0 + nc];
  }
  __syncthreads();
  #pragma unroll
  for (int i = 0; i < 16; ++i) {
    int idx = i*256 + t; int nc = idx >> 6, kr = idx & 63;
    WfcT[(size_t)(n0+nc)*2048 + k0 + kr] = f2bf(tile[kr][nc]);
  }
}

__global__ void conv_x(const float* __restrict__ x, u16* __restrict__ xb, int n)
{
  int i = (blockIdx.x * blockDim.x + threadIdx.x) * 4;
  if (i < n) {
    float4 v = *(const float4*)(x + i);
    u32 lo = (u32)f2bf(v.x) | ((u32)f2bf(v.y) << 16);
    u32 hi = (u32)f2bf(v.z) | ((u32)f2bf(v.w) << 16);
    *(uint2*)(xb + i) = make_uint2(lo, hi);
  }
}

// ---------------------------------------------------------------------------
// Persistent bidirectional LSTM (r5 skeleton + agent-scope IC-resident sync).
// 256 blocks (128/dir), each owns 32 gate-cols (8 h-cols) for all 256 steps.
// B panel resident in 80KB LDS. c in registers. h history in hs (write-once
// per call): producers agent-store (sc1 -> IC); consumers flag-gated normal
// cached loads. Per-wave flags; no __syncthreads in the step loop.
// ---------------------------------------------------------------------------
__global__ __launch_bounds__(256, 1) void lstm_persist(
    const u16* __restrict__ WcF, const u16* __restrict__ WcB,
    const u16* __restrict__ xb,
    const float* __restrict__ bF, const float* __restrict__ bB,
    u16* __restrict__ hs, float* __restrict__ out_tail, int* flags)
{
  extern __shared__ __align__(16) u16 Bs[];   // [NSL][2][64][8]

  // one-time: clear stale lines (poison / previous call) from L1/L2
  __builtin_amdgcn_fence(__ATOMIC_ACQUIRE, "agent");

  const int bid = blockIdx.x;
  const int dir = bid >> 7;
  const int nb  = bid & 127;
  const int n0  = nb * 32;
  const u16* __restrict__ Wc   = dir ? WcB : WcF;
  const float* __restrict__ bias = dir ? bB : bF;

  const int tid  = threadIdx.x;
  const int w    = tid >> 6, lane = tid & 63;
  const int r    = lane & 15, q = lane >> 4, rq = r >> 2;
  int* __restrict__ fl = flags + (dir * 4 + w) * DBLK;

  // stage B panel into LDS: chunk c -> [ks][nt][lane] 16B
  for (int c = tid; c < NSL * 128; c += 256) {
    int ks  = c >> 7;
    int rem = c & 127;
    int nt  = rem >> 6, l2 = rem & 63;
    *(short8*)&Bs[(size_t)c * 8] =
        *(const short8*)(Wc + (size_t)(n0 + nt*16 + (l2 & 15)) * KC + ks*32 + (l2 >> 4)*8);
  }
  #define BSF(ks, nt) (*(const short8*)&Bs[((size_t)(((ks)*2 + (nt))*64 + lane))*8])

  const int jbase = nb * 8;
  float bia[2][4];
  #pragma unroll
  for (int nt = 0; nt < 2; ++nt)
    #pragma unroll
    for (int g = 0; g < 4; ++g)
      bia[nt][g] = bias[g * HID + jbase + 2*rq + nt];

  float creg[2][4];
  #pragma unroll
  for (int nt = 0; nt < 2; ++nt)
    #pragma unroll
    for (int rg = 0; rg < 4; ++rg) creg[nt][rg] = 0.f;

  const int row_a = w * 16 + r;

  // prefetch x fragments for the first step
  short8 xf[8];
  {
    const int tt0 = dir ? (T_SEQ - 1) : 0;
    const u16* axr = xb + ((size_t)tt0 * BATCH + row_a) * INP;
    #pragma unroll
    for (int kx = 0; kx < 8; ++kx) xf[kx] = *(const short8*)(axr + kx*32 + q*8);
  }
  __syncthreads();   // Bs staged (only block-wide barrier)

  // two accumulator chains per nt: accA gets x + first 16 h-slices, accB rest
  f32x4 accA[2], accB[2];
  accA[0] = (f32x4)(0.f); accA[1] = (f32x4)(0.f);
  accB[0] = (f32x4)(0.f); accB[1] = (f32x4)(0.f);
  #pragma unroll
  for (int kx = 0; kx < 8; ++kx) {
    accA[0] = MFMA16(xf[kx], BSF(32 + kx, 0), accA[0]);
    accA[1] = MFMA16(xf[kx], BSF(32 + kx, 1), accA[1]);
  }

  int pf0 = 0, pf1 = 0;   // primed flag values

  for (int s = 0; s < T_SEQ; ++s) {
    const int tt = dir ? (T_SEQ - 1 - s) : s;

    if (s > 0) {
      // wait for all wave-w producers of step s-1 (pf primed last iteration)
      while (!__all((pf0 >= s) && (pf1 >= s))) {
        pf0 = ag_ld_i32(fl + 2*lane);
        pf1 = ag_ld_i32(fl + 2*lane + 1);
      }
      const int tp = dir ? tt + 1 : tt - 1;
      const u16* __restrict__ ar =
          hs + ((size_t)tp * BATCH + row_a) * 2048 + dir * HID;
      short8 hA[32];
      #pragma unroll
      for (int i = 0; i < 32; ++i) hA[i] = *(const short8*)(ar + i*32 + q*8);
      #pragma unroll
      for (int i = 0; i < 16; ++i) {
        accA[0] = MFMA16(hA[i], BSF(i, 0), accA[0]);
        accA[1] = MFMA16(hA[i], BSF(i, 1), accA[1]);
        accB[0] = MFMA16(hA[16 + i], BSF(16 + i, 0), accB[0]);
        accB[1] = MFMA16(hA[16 + i], BSF(16 + i, 1), accB[1]);
      }
    }

    // merge chains + cell update (DPP quad gather; gate = r&3)
    float hnv[2][4];
    #pragma unroll
    for (int nt = 0; nt < 2; ++nt) {
      #pragma unroll
      for (int rg = 0; rg < 4; ++rg) {
        float v  = accA[nt][rg] + accB[nt][rg];
        float x1 = qperm<QP_XOR1>(v);
        float x2 = qperm<QP_XOR2>(v);
        float x3 = qperm<QP_XOR2>(x1);
        float cn = sigm(x1 + bia[nt][1]) * creg[nt][rg] + sigm(v + bia[nt][0]) * tanhf_(x3 + bia[nt][3]);
        float hn = sigm(x2 + bia[nt][2]) * tanhf_(cn);
        creg[nt][rg] = cn; hnv[nt][rg] = hn;
      }
    }
    // packed u32 agent stores: writer lanes (r&3)==0 own cols (jbase+2rq, +1)
    if ((r & 3) == 0) {
      #pragma unroll
      for (int rg = 0; rg < 4; ++rg) {
        int row = w * 16 + q * 4 + rg;
        u32 packed = (u32)f2bf(hnv[0][rg]) | ((u32)f2bf(hnv[1][rg]) << 16);
        ag_st_u32((u32*)(hs + ((size_t)tt * BATCH + row) * 2048 + dir * HID + jbase + 2*rq),
                  packed);
      }
    }

    if (s < T_SEQ - 1) {
      asm volatile("s_waitcnt vmcnt(0)" ::: "memory");   // h stores at IC
      if (lane == 0) ag_st_u32((u32*)(fl + nb), (u32)(s + 1));
      // prime flag loads for the next poll (latency hides under x work)
      pf0 = ag_ld_i32(fl + 2*lane);
      pf1 = ag_ld_i32(fl + 2*lane + 1);
      // next step's x loads + x-MFMAs run before the poll completes
      const int tn = dir ? tt - 1 : tt + 1;
      const u16* axr = xb + ((size_t)tn * BATCH + row_a) * INP;
      #pragma unroll
      for (int kx = 0; kx < 8; ++kx) xf[kx] = *(const short8*)(axr + kx*32 + q*8);
      accA[0] = (f32x4)(0.f); accA[1] = (f32x4)(0.f);
      accB[0] = (f32x4)(0.f); accB[1] = (f32x4)(0.f);
      #pragma unroll
      for (int kx = 0; kx < 8; ++kx) {
        accA[0] = MFMA16(xf[kx], BSF(32 + kx, 0), accA[0]);
        accA[1] = MFMA16(xf[kx], BSF(32 + kx, 1), accA[1]);
      }
    } else {
      // final states ((hF,hB),(cF,cB)); plain stores (kernel-end flush)
      if ((r & 3) == 0) {
        #pragma unroll
        for (int nt = 0; nt < 2; ++nt)
          #pragma unroll
          for (int rg = 0; rg < 4; ++rg) {
            int row = w * 16 + q * 4 + rg;
            int j   = jbase + 2*rq + nt;
            out_tail[dir * (BATCH * HID) + (size_t)row * HID + j] = hnv[nt][rg];
            out_tail[2 * (BATCH * HID) + dir * (BATCH * HID) + (size_t)row * HID + j] = creg[nt][rg];
          }
      }
    }
  }
  #undef BSF
}

// ---------------------------------------------------------------------------
// Final FC: out[16384][1024] = hs[16384][2048] @ WfcT^T + b_fc, f32 out.
// ---------------------------------------------------------------------------
__global__ __launch_bounds__(256) void fc_kernel(
    const u16* __restrict__ hs, const u16* __restrict__ WfcT,
    const float* __restrict__ bfc, float* __restrict__ out)
{
  const int m0 = blockIdx.x * 128, n0 = blockIdx.y * 128;
  __shared__ __align__(16) u16 As[128 * 32];
  __shared__ __align__(16) u16 Bs[128 * 32];
  const int tid = threadIdx.x;
  const int w = tid >> 6, lane = tid & 63;
  const int r = lane & 15, q = lane >> 4;
  const int wy = w >> 1, wx = w & 1;

  f32x4 acc[4][4];
  #pragma unroll
  for (int a = 0; a < 4; ++a)
    #pragma unroll
    for (int b = 0; b < 4; ++b) acc[a][b] = (f32x4)(0.f);

  const int lr = tid >> 1, lk = (tid & 1) * 16;

  for (int k0 = 0; k0 < 2048; k0 += 32) {
    __syncthreads();
    *(short8*)&As[lr * 32 + lk]     = *(const short8*)(hs   + (size_t)(m0 + lr) * 2048 + k0 + lk);
    *(short8*)&As[lr * 32 + lk + 8] = *(const short8*)(hs   + (size_t)(m0 + lr) * 2048 + k0 + lk + 8);
    *(short8*)&Bs[lr * 32 + lk]     = *(const short8*)(WfcT + (size_t)(n0 + lr) * 2048 + k0 + lk);
    *(short8*)&Bs[lr * 32 + lk + 8] = *(const short8*)(WfcT + (size_t)(n0 + lr) * 2048 + k0 + lk + 8);
    __syncthreads();

    short8 af[4], bf[4];
    #pragma unroll
    for (int mt = 0; mt < 4; ++mt)
      af[mt] = *(const short8*)&As[(wy * 64 + mt * 16 + r) * 32 + q * 8];
    #pragma unroll
    for (int nt = 0; nt < 4; ++nt)
      bf[nt] = *(const short8*)&Bs[(wx * 64 + nt * 16 + r) * 32 + q * 8];
    #pragma unroll
    for (int mt = 0; mt < 4; ++mt)
      #pragma unroll
      for (int nt = 0; nt < 4; ++nt)
        acc[mt][nt] = __builtin_amdgcn_mfma_f32_16x16x32_bf16(af[mt], bf[nt], acc[mt][nt], 0, 0, 0);
  }

  #pragma unroll
  for (int mt = 0; mt < 4; ++mt)
    #pragma unroll
    for (int nt = 0; nt < 4; ++nt)
      #pragma unroll
      for (int reg = 0; reg < 4; ++reg) {
        int m = m0 + wy * 64 + mt * 16 + q * 4 + reg;
        int n = n0 + wx * 64 + nt * 16 + r;
        out[(size_t)m * OUTD + n] = acc[mt][nt][reg] + bfc[n];
      }
}

// ---------------------------------------------------------------------------
extern "C" void kernel_launch(void* const* d_in, const int* in_sizes, int n_in,
                              void* d_out, int out_size, void* d_ws, size_t ws_size,
                              hipStream_t stream)
{
  const float* x   = (const float*)d_in[0];
  const float* WxF = (const float*)d_in[1];
  const float* WhF = (const float*)d_in[2];
  const float* bF  = (const float*)d_in[3];
  const float* WxB = (const float*)d_in[4];
  const float* WhB = (const float*)d_in[5];
  const float* bB  = (const float*)d_in[6];
  const float* Wfc = (const float*)d_in[7];
  const float* bfc = (const float*)d_in[8];
  float* out = (float*)d_out;

  char* ws = (char*)d_ws;
  u16*  WcF   = (u16*)(ws + 0);          // 10485760
  u16*  WcB   = (u16*)(ws + 10485760);   // 10485760
  u16*  WfcT  = (u16*)(ws + 20971520);   // 4194304
  u16*  xb    = (u16*)(ws + 25165824);   // 8388608
  u16*  hs    = (u16*)(ws + 34603008);   // 67108864
  int*  flags = (int*)(ws + 101711872);  // 4KB (2 dirs x 4 waves x 128)

  hipMemsetAsync(flags, 0, 4096, stream);   // barrier flags

  hipFuncSetAttribute((const void*)lstm_persist,
                      hipFuncAttributeMaxDynamicSharedMemorySize, LDSB);

  build_wc <<<dim3(KC/64, HID/64, 8), 256, 0, stream>>>(WhF, WxF, WhB, WxB, WcF, WcB);
  build_wfc<<<dim3(2048/64, OUTD/64), 256, 0, stream>>>(Wfc, WfcT);
  conv_x   <<<(T_SEQ*BATCH*INP)/4/256, 256, 0, stream>>>(x, xb, T_SEQ*BATCH*INP);

  lstm_persist<<<NBLK, 256, LDSB, stream>>>(WcF, WcB, xb, bF, bB,
                                            hs, out + 16777216, flags);

  fc_kernel<<<dim3(16384/128, OUTD/128), 256, 0, stream>>>(hs, WfcT, bfc, out);
}